// Round 1
// 317.764 us; speedup vs baseline: 1.0658x; 1.0658x over previous
//
#include <hip/hip_runtime.h>

#define B_ 4
#define T_ 2048
#define C_ 1024
#define H_ 16
#define D_ 64
#define EPS_ 1.1920929e-07f
#define LOG2E_ 1.4426950408889634f

typedef __attribute__((ext_vector_type(8))) short bf16x8;
typedef __attribute__((ext_vector_type(4))) float f32x4;
typedef unsigned short u16;
typedef unsigned int u32;

__device__ inline u16 f2bf(float f) {
  unsigned u = __float_as_uint(f);
  unsigned r = (u + 0x7fffu + ((u >> 16) & 1u)) >> 16;
  return (u16)r;
}

// async global->LDS, 16B per lane (dest = wave-uniform base + lane*16)
__device__ __forceinline__ void gload16(const void* g, void* l) {
  __builtin_amdgcn_global_load_lds(
      (__attribute__((address_space(1))) void*)g,
      (__attribute__((address_space(3))) void*)l, 16, 0, 0);
}

// ---------------- f32 -> bf16 conversion (x) ----------------
__global__ __launch_bounds__(256) void cvt_bf16(const float* __restrict__ src,
                                                u16* __restrict__ dst, int n) {
  const int i = (blockIdx.x * 256 + threadIdx.x) * 4;
  if (i < n) {
    float4 v = *(const float4*)&src[i];
    ushort4 o;
    o.x = f2bf(v.x); o.y = f2bf(v.y); o.z = f2bf(v.z); o.w = f2bf(v.w);
    *(ushort4*)&dst[i] = o;
  }
}

// ---------------- all 4 weights in one launch ----------------
__global__ __launch_bounds__(256) void cvt_weights(const float* __restrict__ wq,
                                                   const float* __restrict__ wk,
                                                   const float* __restrict__ wv,
                                                   const float* __restrict__ wo,
                                                   u16* __restrict__ wqkv,
                                                   u16* __restrict__ wob, int n) {
  const int i = (blockIdx.x * 256 + threadIdx.x) * 4;
  const int t = blockIdx.y;
  const float* src = (t == 0) ? wq : (t == 1) ? wk : (t == 2) ? wv : wo;
  u16* dst = (t == 3) ? wob : (wqkv + (size_t)t * n);
  if (i < n) {
    float4 v = *(const float4*)&src[i];
    ushort4 o;
    o.x = f2bf(v.x); o.y = f2bf(v.y); o.z = f2bf(v.z); o.w = f2bf(v.w);
    *(ushort4*)&dst[i] = o;
  }
}

// ---------------- fused QKV GEMM: [Q|K|V] = X @ Wqkv^T + epilogues ----------------
// X: (M,1024) bf16, Wqkv: (3072,1024) bf16. 128x128 tile, BK=64, 4 waves.
// Staging via global_load_lds width=16 (m97 structure).
// blockIdx.x: 0..7 -> Q (rope+rms, *scale*log2e), 8..15 -> K (rope+rms), 16..23 -> V.
__global__ __launch_bounds__(256) void gemm_qkv(const u16* __restrict__ X,
                                                const u16* __restrict__ W,
                                                u16* __restrict__ qb,
                                                u16* __restrict__ kb,
                                                u16* __restrict__ vb,
                                                const float* __restrict__ cs,
                                                const float* __restrict__ sn,
                                                int M, int K) {
  __shared__ short As[128 * 64];
  __shared__ short Bs[128 * 64];
  const int tid = threadIdx.x;
  const int lane = tid & 63;
  const int w = tid >> 6;
  const int wr = w >> 1, wc = w & 1;
  const int m0 = blockIdx.y * 128, n0 = blockIdx.x * 128;
  const int lrow = lane >> 3;       // 0..7 within an 8-row chunk
  const int lcol = (lane & 7) * 8;  // u16 col within a 64-col row

  f32x4 acc[4][4];
#pragma unroll
  for (int mi = 0; mi < 4; ++mi)
#pragma unroll
    for (int ni = 0; ni < 4; ++ni)
      acc[mi][ni] = (f32x4){0.f, 0.f, 0.f, 0.f};

  const int r = lane & 15;
  const int quad = lane >> 4;

  for (int kt = 0; kt < K; kt += 64) {
#pragma unroll
    for (int i = 0; i < 4; ++i) {
      const int row = w * 32 + i * 8;  // wave-uniform LDS dest row
      gload16(&X[(size_t)(m0 + row + lrow) * K + kt + lcol], &As[row * 64]);
      gload16(&W[(size_t)(n0 + row + lrow) * K + kt + lcol], &Bs[row * 64]);
    }
    __syncthreads();
#pragma unroll
    for (int kc = 0; kc < 2; ++kc) {
      const int ko = kc * 32 + quad * 8;
      bf16x8 a[4], b[4];
#pragma unroll
      for (int mi = 0; mi < 4; ++mi)
        a[mi] = *(const bf16x8*)&As[(wr * 64 + mi * 16 + r) * 64 + ko];
#pragma unroll
      for (int ni = 0; ni < 4; ++ni)
        b[ni] = *(const bf16x8*)&Bs[(wc * 64 + ni * 16 + r) * 64 + ko];
#pragma unroll
      for (int mi = 0; mi < 4; ++mi)
#pragma unroll
        for (int ni = 0; ni < 4; ++ni)
          acc[mi][ni] = __builtin_amdgcn_mfma_f32_16x16x32_bf16(a[mi], b[ni], acc[mi][ni], 0, 0, 0);
    }
    __syncthreads();
  }

  const int which = blockIdx.x >> 3;                // 0=Q 1=K 2=V
  const int c0 = (blockIdx.x & 7) * 128 + wc * 64;  // column within tensor (one head/wave)
  u16* dst = (which == 0) ? qb : (which == 1) ? kb : vb;

  if (which < 2) {
    // fused RoPE + RMSNorm; d = ni*16+r, pair (d,d+32) = (ni,ni+2) in-lane
#pragma unroll
    for (int mi = 0; mi < 4; ++mi)
#pragma unroll
      for (int j = 0; j < 4; ++j) {
        const int gr = m0 + wr * 64 + mi * 16 + quad * 4 + j;
        const int t = gr & (T_ - 1);
        float o[4];
#pragma unroll
        for (int ni = 0; ni < 2; ++ni) {
          const float c = cs[t * 32 + ni * 16 + r];
          const float s = sn[t * 32 + ni * 16 + r];
          const float x1 = acc[mi][ni][j], x2 = acc[mi][ni + 2][j];
          o[ni]     = x1 * c + x2 * s;
          o[ni + 2] = x2 * c - x1 * s;
        }
        float sq = o[0] * o[0] + o[1] * o[1] + o[2] * o[2] + o[3] * o[3];
        sq += __shfl_xor(sq, 1, 64);
        sq += __shfl_xor(sq, 2, 64);
        sq += __shfl_xor(sq, 4, 64);
        sq += __shfl_xor(sq, 8, 64);
        float rn = rsqrtf(sq * (1.0f / 64.0f) + EPS_);
        if (which == 0) rn *= 0.125f * LOG2E_;  // fold attn scale AND log2(e) into Q
#pragma unroll
        for (int ni = 0; ni < 4; ++ni)
          dst[(size_t)gr * C_ + c0 + ni * 16 + r] = f2bf(o[ni] * rn);
      }
  } else {
#pragma unroll
    for (int mi = 0; mi < 4; ++mi)
#pragma unroll
      for (int ni = 0; ni < 4; ++ni) {
        const int gc = c0 + ni * 16 + r;
#pragma unroll
        for (int j = 0; j < 4; ++j) {
          const int gr = m0 + wr * 64 + mi * 16 + quad * 4 + j;
          dst[(size_t)gr * C_ + gc] = f2bf(acc[mi][ni][j]);
        }
      }
  }
}

// ---------------- output GEMM: out = Y @ Wo^T (fp32 out) ----------------
__global__ __launch_bounds__(256) void gemm_out(const u16* __restrict__ X,
                                                const u16* __restrict__ W,
                                                float* __restrict__ Y,
                                                int M, int N, int K) {
  __shared__ short As[128 * 64];
  __shared__ short Bs[128 * 64];
  const int tid = threadIdx.x;
  const int lane = tid & 63;
  const int w = tid >> 6;
  const int wr = w >> 1, wc = w & 1;
  const int m0 = blockIdx.y * 128, n0 = blockIdx.x * 128;
  const int lrow = lane >> 3;
  const int lcol = (lane & 7) * 8;

  f32x4 acc[4][4];
#pragma unroll
  for (int mi = 0; mi < 4; ++mi)
#pragma unroll
    for (int ni = 0; ni < 4; ++ni)
      acc[mi][ni] = (f32x4){0.f, 0.f, 0.f, 0.f};

  const int r = lane & 15;
  const int quad = lane >> 4;

  for (int kt = 0; kt < K; kt += 64) {
#pragma unroll
    for (int i = 0; i < 4; ++i) {
      const int row = w * 32 + i * 8;
      gload16(&X[(size_t)(m0 + row + lrow) * K + kt + lcol], &As[row * 64]);
      gload16(&W[(size_t)(n0 + row + lrow) * K + kt + lcol], &Bs[row * 64]);
    }
    __syncthreads();
#pragma unroll
    for (int kc = 0; kc < 2; ++kc) {
      const int ko = kc * 32 + quad * 8;
      bf16x8 a[4], b[4];
#pragma unroll
      for (int mi = 0; mi < 4; ++mi)
        a[mi] = *(const bf16x8*)&As[(wr * 64 + mi * 16 + r) * 64 + ko];
#pragma unroll
      for (int ni = 0; ni < 4; ++ni)
        b[ni] = *(const bf16x8*)&Bs[(wc * 64 + ni * 16 + r) * 64 + ko];
#pragma unroll
      for (int mi = 0; mi < 4; ++mi)
#pragma unroll
        for (int ni = 0; ni < 4; ++ni)
          acc[mi][ni] = __builtin_amdgcn_mfma_f32_16x16x32_bf16(a[mi], b[ni], acc[mi][ni], 0, 0, 0);
    }
    __syncthreads();
  }

#pragma unroll
  for (int mi = 0; mi < 4; ++mi)
#pragma unroll
    for (int ni = 0; ni < 4; ++ni) {
      const int gc = n0 + wc * 64 + ni * 16 + r;
#pragma unroll
      for (int j = 0; j < 4; ++j) {
        const int gr = m0 + wr * 64 + mi * 16 + quad * 4 + j;
        Y[(size_t)gr * N + gc] = acc[mi][ni][j];
      }
    }
}

// ---------------- MFMA flash attention, fixed-shift softmax ----------------
// Q carries 0.125*log2e -> p = exp2(s), single v_exp_f32 per element.
// |s| <= 8*log2e ~ 11.54 -> p <= 2^11.6, safe without running max.
// Key<->slot permutation: slot = (key&15)*4 + (key>>4), applied to P-writes and
// Vt staging consistently -> P row writes become one ds_write_b64.
// Restructured: kf/vf fragments hoisted out of the qg loop (LDS b128 reads
// per tile per wave: 36 -> 20); P packed with v_cvt_pk_bf16_f32.
// grid=(T/128, B*H), block=256; wave w owns queries [w*32, w*32+32).
__global__ __launch_bounds__(256) void flash_mfma(const u16* __restrict__ Qb,
                                                  const u16* __restrict__ Kb,
                                                  const u16* __restrict__ Vb,
                                                  u16* __restrict__ Yb) {
  __shared__ u16 Ks[64][72];
  __shared__ u16 Vt[64][72];   // Vt[d][slot]
  __shared__ u16 Ps[128][72];  // Q staging, then P tiles (wave-local rows), [q][slot]
  const int tid = threadIdx.x;
  const int lane = tid & 63;
  const int w = tid >> 6;
  const int r = lane & 15;
  const int quad = lane >> 4;
  const int qt = blockIdx.x, bh = blockIdx.y;
  const int b = bh >> 4, h = bh & 15;
  const int srow = lane;
  const int sd0 = w * 16;
  const int vslot = (srow & 15) * 4 + (srow >> 4);  // slot for key=srow

  // stage Q tile (128 x 64): 2 threads per row
  {
    const int row = tid >> 1, half = tid & 1;
    const size_t g = ((size_t)((b * T_ + qt * 128 + row) * H_ + h)) * D_ + half * 32;
    *(bf16x8*)&Ps[row][half * 32]      = *(const bf16x8*)&Qb[g];
    *(bf16x8*)&Ps[row][half * 32 + 8]  = *(const bf16x8*)&Qb[g + 8];
    *(bf16x8*)&Ps[row][half * 32 + 16] = *(const bf16x8*)&Qb[g + 16];
    *(bf16x8*)&Ps[row][half * 32 + 24] = *(const bf16x8*)&Qb[g + 24];
  }
  __syncthreads();
  bf16x8 qf[2][2];
#pragma unroll
  for (int qg = 0; qg < 2; ++qg)
#pragma unroll
    for (int kc = 0; kc < 2; ++kc)
      qf[qg][kc] = *(const bf16x8*)&Ps[w * 32 + qg * 16 + r][kc * 32 + quad * 8];

  f32x4 oacc[2][4];
#pragma unroll
  for (int qg = 0; qg < 2; ++qg)
#pragma unroll
    for (int ni = 0; ni < 4; ++ni) oacc[qg][ni] = (f32x4){0.f, 0.f, 0.f, 0.f};
  float l_i[2][4];
#pragma unroll
  for (int qg = 0; qg < 2; ++qg)
#pragma unroll
    for (int j = 0; j < 4; ++j) l_i[qg][j] = 0.f;

  bf16x8 k0, k1, v0, v1;
  {
    const size_t g = ((size_t)((b * T_ + srow) * H_ + h)) * D_ + sd0;
    k0 = *(const bf16x8*)&Kb[g];
    k1 = *(const bf16x8*)&Kb[g + 8];
    v0 = *(const bf16x8*)&Vb[g];
    v1 = *(const bf16x8*)&Vb[g + 8];
  }

  for (int kt = 0; kt < T_; kt += 64) {
    *(bf16x8*)&Ks[srow][sd0] = k0;
    *(bf16x8*)&Ks[srow][sd0 + 8] = k1;
#pragma unroll
    for (int i = 0; i < 8; ++i) Vt[sd0 + i][vslot] = (u16)v0[i];
#pragma unroll
    for (int i = 0; i < 8; ++i) Vt[sd0 + 8 + i][vslot] = (u16)v1[i];
    __syncthreads();
    if (kt + 64 < T_) {
      const size_t g = ((size_t)((b * T_ + kt + 64 + srow) * H_ + h)) * D_ + sd0;
      k0 = *(const bf16x8*)&Kb[g];
      k1 = *(const bf16x8*)&Kb[g + 8];
      v0 = *(const bf16x8*)&Vb[g];
      v1 = *(const bf16x8*)&Vb[g + 8];
    }

    // QK^T, kf shared across both qg
    f32x4 s[2][4];
#pragma unroll
    for (int qg = 0; qg < 2; ++qg)
#pragma unroll
      for (int ni = 0; ni < 4; ++ni) s[qg][ni] = (f32x4){0.f, 0.f, 0.f, 0.f};
#pragma unroll
    for (int ni = 0; ni < 4; ++ni)
#pragma unroll
      for (int kc = 0; kc < 2; ++kc) {
        bf16x8 kf = *(const bf16x8*)&Ks[ni * 16 + r][kc * 32 + quad * 8];
        s[0][ni] = __builtin_amdgcn_mfma_f32_16x16x32_bf16(qf[0][kc], kf, s[0][ni], 0, 0, 0);
        s[1][ni] = __builtin_amdgcn_mfma_f32_16x16x32_bf16(qf[1][kc], kf, s[1][ni], 0, 0, 0);
      }

    // softmax: p = exp2(s), per-lane partial l, packed P write via cvt_pk
#pragma unroll
    for (int qg = 0; qg < 2; ++qg)
#pragma unroll
      for (int j = 0; j < 4; ++j) {
        const float p0 = __builtin_amdgcn_exp2f(s[qg][0][j]);
        const float p1 = __builtin_amdgcn_exp2f(s[qg][1][j]);
        const float p2 = __builtin_amdgcn_exp2f(s[qg][2][j]);
        const float p3 = __builtin_amdgcn_exp2f(s[qg][3][j]);
        l_i[qg][j] += (p0 + p1) + (p2 + p3);
        u32 lo, hi;
        asm("v_cvt_pk_bf16_f32 %0, %1, %2" : "=v"(lo) : "v"(p0), "v"(p1));
        asm("v_cvt_pk_bf16_f32 %0, %1, %2" : "=v"(hi) : "v"(p2), "v"(p3));
        const int prow = w * 32 + qg * 16 + quad * 4 + j;
        *(uint2*)&Ps[prow][r * 4] = make_uint2(lo, hi);  // slots r*4 + ni
      }

    // O += P @ V (slot space), vf shared across both qg
#pragma unroll
    for (int kc = 0; kc < 2; ++kc) {
      bf16x8 vf[4];
#pragma unroll
      for (int ni = 0; ni < 4; ++ni)
        vf[ni] = *(const bf16x8*)&Vt[ni * 16 + r][kc * 32 + quad * 8];
#pragma unroll
      for (int qg = 0; qg < 2; ++qg) {
        bf16x8 pf = *(const bf16x8*)&Ps[w * 32 + qg * 16 + r][kc * 32 + quad * 8];
#pragma unroll
        for (int ni = 0; ni < 4; ++ni)
          oacc[qg][ni] = __builtin_amdgcn_mfma_f32_16x16x32_bf16(pf, vf[ni], oacc[qg][ni], 0, 0, 0);
      }
    }
    __syncthreads();
  }

  // epilogue: reduce l across the 16 lanes holding each row, scale, store bf16
#pragma unroll
  for (int qg = 0; qg < 2; ++qg)
#pragma unroll
    for (int j = 0; j < 4; ++j) {
      float l = l_i[qg][j];
      l += __shfl_xor(l, 1, 64);
      l += __shfl_xor(l, 2, 64);
      l += __shfl_xor(l, 4, 64);
      l += __shfl_xor(l, 8, 64);
      const float inv = 1.0f / l;
      const int t = qt * 128 + w * 32 + qg * 16 + quad * 4 + j;
      const size_t gbase = ((size_t)((b * T_ + t) * H_ + h)) * D_;
#pragma unroll
      for (int ni = 0; ni < 4; ++ni)
        Yb[gbase + ni * 16 + r] = f2bf(oacc[qg][ni][j] * inv);
    }
}

extern "C" void kernel_launch(void* const* d_in, const int* in_sizes, int n_in,
                              void* d_out, int out_size, void* d_ws, size_t ws_size,
                              hipStream_t stream) {
  const float* x    = (const float*)d_in[0];
  const float* cosb = (const float*)d_in[1];
  const float* sinb = (const float*)d_in[2];
  const float* Wq   = (const float*)d_in[3];
  const float* Wk   = (const float*)d_in[4];
  const float* Wv   = (const float*)d_in[5];
  const float* Wo   = (const float*)d_in[6];
  float* out = (float*)d_out;

  const size_t NE = (size_t)B_ * T_ * C_;  // 8M elements
  const int CC = C_ * C_;                  // 1M elements
  // workspace (~72 MB): xb,qb,kb,vb bf16 (64 MB) + wqkv (6 MB) + wob (2 MB)
  u16* xb   = (u16*)d_ws;
  u16* qb   = xb + NE;
  u16* kb   = qb + NE;
  u16* vb   = kb + NE;
  u16* wqkv = vb + NE;
  u16* wob  = wqkv + 3 * (size_t)CC;
  u16* yb   = xb;  // xb dead after QKV GEMM; reuse for attention output

  const int M = B_ * T_;  // 8192

  cvt_bf16<<<(int)(NE / 1024), 256, 0, stream>>>(x, xb, (int)NE);
  dim3 wg(CC / 1024, 4);
  cvt_weights<<<wg, 256, 0, stream>>>(Wq, Wk, Wv, Wo, wqkv, wob, CC);

  dim3 qg(24, M / 128), gb(256);
  gemm_qkv<<<qg, gb, 0, stream>>>(xb, wqkv, qb, kb, vb, cosb, sinb, M, C_);

  dim3 fg(T_ / 128, B_ * H_);
  flash_mfma<<<fg, 256, 0, stream>>>(qb, kb, vb, yb);

  dim3 og(C_ / 128, M / 128);
  gemm_out<<<og, gb, 0, stream>>>(yb, wob, out, M, C_, C_);
}

// Round 2
// 309.143 us; speedup vs baseline: 1.0956x; 1.0279x over previous
//
#include <hip/hip_runtime.h>

#define B_ 4
#define T_ 2048
#define C_ 1024
#define H_ 16
#define D_ 64
#define EPS_ 1.1920929e-07f
#define LOG2E_ 1.4426950408889634f

typedef __attribute__((ext_vector_type(8))) short bf16x8;
typedef __attribute__((ext_vector_type(4))) float f32x4;
typedef unsigned short u16;
typedef unsigned int u32;

__device__ inline u16 f2bf(float f) {
  unsigned u = __float_as_uint(f);
  unsigned r = (u + 0x7fffu + ((u >> 16) & 1u)) >> 16;
  return (u16)r;
}

// async global->LDS, 16B per lane (dest = wave-uniform base + lane*16)
__device__ __forceinline__ void gload16(const void* g, void* l) {
  __builtin_amdgcn_global_load_lds(
      (__attribute__((address_space(1))) void*)g,
      (__attribute__((address_space(3))) void*)l, 16, 0, 0);
}

// ---------------- f32 -> bf16 conversion (x) ----------------
__global__ __launch_bounds__(256) void cvt_bf16(const float* __restrict__ src,
                                                u16* __restrict__ dst, int n) {
  const int i = (blockIdx.x * 256 + threadIdx.x) * 4;
  if (i < n) {
    float4 v = *(const float4*)&src[i];
    ushort4 o;
    o.x = f2bf(v.x); o.y = f2bf(v.y); o.z = f2bf(v.z); o.w = f2bf(v.w);
    *(ushort4*)&dst[i] = o;
  }
}

// ---------------- all 4 weights in one launch ----------------
__global__ __launch_bounds__(256) void cvt_weights(const float* __restrict__ wq,
                                                   const float* __restrict__ wk,
                                                   const float* __restrict__ wv,
                                                   const float* __restrict__ wo,
                                                   u16* __restrict__ wqkv,
                                                   u16* __restrict__ wob, int n) {
  const int i = (blockIdx.x * 256 + threadIdx.x) * 4;
  const int t = blockIdx.y;
  const float* src = (t == 0) ? wq : (t == 1) ? wk : (t == 2) ? wv : wo;
  u16* dst = (t == 3) ? wob : (wqkv + (size_t)t * n);
  if (i < n) {
    float4 v = *(const float4*)&src[i];
    ushort4 o;
    o.x = f2bf(v.x); o.y = f2bf(v.y); o.z = f2bf(v.z); o.w = f2bf(v.w);
    *(ushort4*)&dst[i] = o;
  }
}

// ---------------- fused QKV GEMM: [Q|K|V] = X @ Wqkv^T + epilogues ----------------
// X: (M,1024) bf16, Wqkv: (3072,1024) bf16. 128x128 tile, BK=64, 4 waves.
// Staging via global_load_lds width=16 (m97 structure).
// blockIdx.x: 0..7 -> Q (rope+rms, *scale*log2e), 8..15 -> K (rope+rms),
// 16..23 -> V (stored TRANSPOSED + slot-permuted: vtb[(bh*64+d)*T + tpos],
// tpos within each 64-key tile = slot(key) = (key&15)*4 + (key>>4), so flash
// can stage Vt[d][slot] with contiguous b128 loads -- no in-flash transpose).
__global__ __launch_bounds__(256) void gemm_qkv(const u16* __restrict__ X,
                                                const u16* __restrict__ W,
                                                u16* __restrict__ qb,
                                                u16* __restrict__ kb,
                                                u16* __restrict__ vtb,
                                                const float* __restrict__ cs,
                                                const float* __restrict__ sn,
                                                int M, int K) {
  __shared__ short As[128 * 64];
  __shared__ short Bs[128 * 64];
  const int tid = threadIdx.x;
  const int lane = tid & 63;
  const int w = tid >> 6;
  const int wr = w >> 1, wc = w & 1;
  const int m0 = blockIdx.y * 128, n0 = blockIdx.x * 128;
  const int lrow = lane >> 3;       // 0..7 within an 8-row chunk
  const int lcol = (lane & 7) * 8;  // u16 col within a 64-col row

  f32x4 acc[4][4];
#pragma unroll
  for (int mi = 0; mi < 4; ++mi)
#pragma unroll
    for (int ni = 0; ni < 4; ++ni)
      acc[mi][ni] = (f32x4){0.f, 0.f, 0.f, 0.f};

  const int r = lane & 15;
  const int quad = lane >> 4;

  for (int kt = 0; kt < K; kt += 64) {
#pragma unroll
    for (int i = 0; i < 4; ++i) {
      const int row = w * 32 + i * 8;  // wave-uniform LDS dest row
      gload16(&X[(size_t)(m0 + row + lrow) * K + kt + lcol], &As[row * 64]);
      gload16(&W[(size_t)(n0 + row + lrow) * K + kt + lcol], &Bs[row * 64]);
    }
    __syncthreads();
#pragma unroll
    for (int kc = 0; kc < 2; ++kc) {
      const int ko = kc * 32 + quad * 8;
      bf16x8 a[4], b[4];
#pragma unroll
      for (int mi = 0; mi < 4; ++mi)
        a[mi] = *(const bf16x8*)&As[(wr * 64 + mi * 16 + r) * 64 + ko];
#pragma unroll
      for (int ni = 0; ni < 4; ++ni)
        b[ni] = *(const bf16x8*)&Bs[(wc * 64 + ni * 16 + r) * 64 + ko];
#pragma unroll
      for (int mi = 0; mi < 4; ++mi)
#pragma unroll
        for (int ni = 0; ni < 4; ++ni)
          acc[mi][ni] = __builtin_amdgcn_mfma_f32_16x16x32_bf16(a[mi], b[ni], acc[mi][ni], 0, 0, 0);
    }
    __syncthreads();
  }

  const int which = blockIdx.x >> 3;                // 0=Q 1=K 2=V
  const int c0 = (blockIdx.x & 7) * 128 + wc * 64;  // column within tensor (one head/wave)

  if (which < 2) {
    u16* dst = (which == 0) ? qb : kb;
    // fused RoPE + RMSNorm; d = ni*16+r, pair (d,d+32) = (ni,ni+2) in-lane
#pragma unroll
    for (int mi = 0; mi < 4; ++mi)
#pragma unroll
      for (int j = 0; j < 4; ++j) {
        const int gr = m0 + wr * 64 + mi * 16 + quad * 4 + j;
        const int t = gr & (T_ - 1);
        float o[4];
#pragma unroll
        for (int ni = 0; ni < 2; ++ni) {
          const float c = cs[t * 32 + ni * 16 + r];
          const float s = sn[t * 32 + ni * 16 + r];
          const float x1 = acc[mi][ni][j], x2 = acc[mi][ni + 2][j];
          o[ni]     = x1 * c + x2 * s;
          o[ni + 2] = x2 * c - x1 * s;
        }
        float sq = o[0] * o[0] + o[1] * o[1] + o[2] * o[2] + o[3] * o[3];
        sq += __shfl_xor(sq, 1, 64);
        sq += __shfl_xor(sq, 2, 64);
        sq += __shfl_xor(sq, 4, 64);
        sq += __shfl_xor(sq, 8, 64);
        float rn = rsqrtf(sq * (1.0f / 64.0f) + EPS_);
        if (which == 0) rn *= 0.125f * LOG2E_;  // fold attn scale AND log2(e) into Q
#pragma unroll
        for (int ni = 0; ni < 4; ++ni)
          dst[(size_t)gr * C_ + c0 + ni * 16 + r] = f2bf(o[ni] * rn);
      }
  } else {
    // V: transposed + slot-permuted store. head h = c0/64, d = ni*16+r.
    // key-in-tile = mi*16 + quad*4 + j -> slot = (quad*4+j)*4 + mi,
    // so (j,mi) for fixed (ni) are 16 CONTIGUOUS u16 at tbase + quad*16.
    const int h = (blockIdx.x & 7) * 2 + wc;
    const int gr0 = m0 + wr * 64;
    const int bb = gr0 >> 11;         // batch (T_=2048)
    const int tbase = gr0 & (T_ - 1); // multiple of 64
#pragma unroll
    for (int ni = 0; ni < 4; ++ni) {
      const int d = ni * 16 + r;
      bf16x8 o0, o1;
#pragma unroll
      for (int mi = 0; mi < 4; ++mi)
#pragma unroll
        for (int j = 0; j < 4; ++j) {
          const int idx = j * 4 + mi;
          const u16 vv = f2bf(acc[mi][ni][j]);
          if (idx < 8) o0[idx] = (short)vv; else o1[idx - 8] = (short)vv;
        }
      u16* p = &vtb[((size_t)((bb * H_ + h) * D_ + d)) * T_ + tbase + quad * 16];
      *(bf16x8*)&p[0] = o0;
      *(bf16x8*)&p[8] = o1;
    }
  }
}

// ---------------- output GEMM: out = Y @ Wo^T (fp32 out) ----------------
__global__ __launch_bounds__(256) void gemm_out(const u16* __restrict__ X,
                                                const u16* __restrict__ W,
                                                float* __restrict__ Y,
                                                int M, int N, int K) {
  __shared__ short As[128 * 64];
  __shared__ short Bs[128 * 64];
  const int tid = threadIdx.x;
  const int lane = tid & 63;
  const int w = tid >> 6;
  const int wr = w >> 1, wc = w & 1;
  const int m0 = blockIdx.y * 128, n0 = blockIdx.x * 128;
  const int lrow = lane >> 3;
  const int lcol = (lane & 7) * 8;

  f32x4 acc[4][4];
#pragma unroll
  for (int mi = 0; mi < 4; ++mi)
#pragma unroll
    for (int ni = 0; ni < 4; ++ni)
      acc[mi][ni] = (f32x4){0.f, 0.f, 0.f, 0.f};

  const int r = lane & 15;
  const int quad = lane >> 4;

  for (int kt = 0; kt < K; kt += 64) {
#pragma unroll
    for (int i = 0; i < 4; ++i) {
      const int row = w * 32 + i * 8;
      gload16(&X[(size_t)(m0 + row + lrow) * K + kt + lcol], &As[row * 64]);
      gload16(&W[(size_t)(n0 + row + lrow) * K + kt + lcol], &Bs[row * 64]);
    }
    __syncthreads();
#pragma unroll
    for (int kc = 0; kc < 2; ++kc) {
      const int ko = kc * 32 + quad * 8;
      bf16x8 a[4], b[4];
#pragma unroll
      for (int mi = 0; mi < 4; ++mi)
        a[mi] = *(const bf16x8*)&As[(wr * 64 + mi * 16 + r) * 64 + ko];
#pragma unroll
      for (int ni = 0; ni < 4; ++ni)
        b[ni] = *(const bf16x8*)&Bs[(wc * 64 + ni * 16 + r) * 64 + ko];
#pragma unroll
      for (int mi = 0; mi < 4; ++mi)
#pragma unroll
        for (int ni = 0; ni < 4; ++ni)
          acc[mi][ni] = __builtin_amdgcn_mfma_f32_16x16x32_bf16(a[mi], b[ni], acc[mi][ni], 0, 0, 0);
    }
    __syncthreads();
  }

#pragma unroll
  for (int mi = 0; mi < 4; ++mi)
#pragma unroll
    for (int ni = 0; ni < 4; ++ni) {
      const int gc = n0 + wc * 64 + ni * 16 + r;
#pragma unroll
      for (int j = 0; j < 4; ++j) {
        const int gr = m0 + wr * 64 + mi * 16 + quad * 4 + j;
        Y[(size_t)gr * N + gc] = acc[mi][ni][j];
      }
    }
}

// ---------------- MFMA flash attention, fixed-shift softmax ----------------
// Q carries 0.125*log2e -> p = exp2(s). |s| <= 8*log2e -> safe, no running max.
// V arrives pre-transposed + slot-permuted (vtb[(bh*64+d)*T + kt + slot]) so
// Vt staging is 2 contiguous b128 loads + 2 ds_write_b128 per thread (was
// 16 ds_write_b16 scatter). LDS ops/thread/tile: 46 -> 32.
// grid=(B*H, T/128): all qt-blocks of one head land on one XCD (bid%8=bh%8)
// -> K/V served from that XCD's L2 (4 MB working set per XCD).
__global__ __launch_bounds__(256) void flash_mfma(const u16* __restrict__ Qb,
                                                  const u16* __restrict__ Kb,
                                                  const u16* __restrict__ Vtb,
                                                  u16* __restrict__ Yb) {
  __shared__ u16 Ks[64][72];
  __shared__ u16 Vt[64][72];   // Vt[d][slot]
  __shared__ u16 Ps[128][72];  // Q staging, then P tiles (wave-local rows), [q][slot]
  const int tid = threadIdx.x;
  const int lane = tid & 63;
  const int w = tid >> 6;
  const int r = lane & 15;
  const int quad = lane >> 4;
  const int bh = blockIdx.x, qt = blockIdx.y;
  const int b = bh >> 4, h = bh & 15;
  const int srow = lane;
  const int sd0 = w * 16;
  const int vrow = tid >> 2;        // d row 0..63 for Vt staging
  const int vco = (tid & 3) * 16;   // slot offset 0/16/32/48

  // stage Q tile (128 x 64): 2 threads per row
  {
    const int row = tid >> 1, half = tid & 1;
    const size_t g = ((size_t)((b * T_ + qt * 128 + row) * H_ + h)) * D_ + half * 32;
    *(bf16x8*)&Ps[row][half * 32]      = *(const bf16x8*)&Qb[g];
    *(bf16x8*)&Ps[row][half * 32 + 8]  = *(const bf16x8*)&Qb[g + 8];
    *(bf16x8*)&Ps[row][half * 32 + 16] = *(const bf16x8*)&Qb[g + 16];
    *(bf16x8*)&Ps[row][half * 32 + 24] = *(const bf16x8*)&Qb[g + 24];
  }
  __syncthreads();
  bf16x8 qf[2][2];
#pragma unroll
  for (int qg = 0; qg < 2; ++qg)
#pragma unroll
    for (int kc = 0; kc < 2; ++kc)
      qf[qg][kc] = *(const bf16x8*)&Ps[w * 32 + qg * 16 + r][kc * 32 + quad * 8];

  f32x4 oacc[2][4];
#pragma unroll
  for (int qg = 0; qg < 2; ++qg)
#pragma unroll
    for (int ni = 0; ni < 4; ++ni) oacc[qg][ni] = (f32x4){0.f, 0.f, 0.f, 0.f};
  float l_i[2][4];
#pragma unroll
  for (int qg = 0; qg < 2; ++qg)
#pragma unroll
    for (int j = 0; j < 4; ++j) l_i[qg][j] = 0.f;

  bf16x8 k0, k1, v0, v1;
  {
    const size_t gk = ((size_t)((b * T_ + srow) * H_ + h)) * D_ + sd0;
    k0 = *(const bf16x8*)&Kb[gk];
    k1 = *(const bf16x8*)&Kb[gk + 8];
    const size_t gv = ((size_t)(bh * 64 + vrow)) * T_ + vco;
    v0 = *(const bf16x8*)&Vtb[gv];
    v1 = *(const bf16x8*)&Vtb[gv + 8];
  }

  for (int kt = 0; kt < T_; kt += 64) {
    *(bf16x8*)&Ks[srow][sd0] = k0;
    *(bf16x8*)&Ks[srow][sd0 + 8] = k1;
    *(bf16x8*)&Vt[vrow][vco] = v0;
    *(bf16x8*)&Vt[vrow][vco + 8] = v1;
    __syncthreads();
    if (kt + 64 < T_) {
      const size_t gk = ((size_t)((b * T_ + kt + 64 + srow) * H_ + h)) * D_ + sd0;
      k0 = *(const bf16x8*)&Kb[gk];
      k1 = *(const bf16x8*)&Kb[gk + 8];
      const size_t gv = ((size_t)(bh * 64 + vrow)) * T_ + kt + 64 + vco;
      v0 = *(const bf16x8*)&Vtb[gv];
      v1 = *(const bf16x8*)&Vtb[gv + 8];
    }

    // QK^T, kf shared across both qg
    f32x4 s[2][4];
#pragma unroll
    for (int qg = 0; qg < 2; ++qg)
#pragma unroll
      for (int ni = 0; ni < 4; ++ni) s[qg][ni] = (f32x4){0.f, 0.f, 0.f, 0.f};
#pragma unroll
    for (int ni = 0; ni < 4; ++ni)
#pragma unroll
      for (int kc = 0; kc < 2; ++kc) {
        bf16x8 kf = *(const bf16x8*)&Ks[ni * 16 + r][kc * 32 + quad * 8];
        s[0][ni] = __builtin_amdgcn_mfma_f32_16x16x32_bf16(qf[0][kc], kf, s[0][ni], 0, 0, 0);
        s[1][ni] = __builtin_amdgcn_mfma_f32_16x16x32_bf16(qf[1][kc], kf, s[1][ni], 0, 0, 0);
      }

    // softmax: p = exp2(s), per-lane partial l, packed P write via cvt_pk
#pragma unroll
    for (int qg = 0; qg < 2; ++qg)
#pragma unroll
      for (int j = 0; j < 4; ++j) {
        const float p0 = __builtin_amdgcn_exp2f(s[qg][0][j]);
        const float p1 = __builtin_amdgcn_exp2f(s[qg][1][j]);
        const float p2 = __builtin_amdgcn_exp2f(s[qg][2][j]);
        const float p3 = __builtin_amdgcn_exp2f(s[qg][3][j]);
        l_i[qg][j] += (p0 + p1) + (p2 + p3);
        u32 lo, hi;
        asm("v_cvt_pk_bf16_f32 %0, %1, %2" : "=v"(lo) : "v"(p0), "v"(p1));
        asm("v_cvt_pk_bf16_f32 %0, %1, %2" : "=v"(hi) : "v"(p2), "v"(p3));
        const int prow = w * 32 + qg * 16 + quad * 4 + j;
        *(uint2*)&Ps[prow][r * 4] = make_uint2(lo, hi);  // slots r*4 + ni
      }

    // O += P @ V (slot space), vf shared across both qg
#pragma unroll
    for (int kc = 0; kc < 2; ++kc) {
      bf16x8 vf[4];
#pragma unroll
      for (int ni = 0; ni < 4; ++ni)
        vf[ni] = *(const bf16x8*)&Vt[ni * 16 + r][kc * 32 + quad * 8];
#pragma unroll
      for (int qg = 0; qg < 2; ++qg) {
        bf16x8 pf = *(const bf16x8*)&Ps[w * 32 + qg * 16 + r][kc * 32 + quad * 8];
#pragma unroll
        for (int ni = 0; ni < 4; ++ni)
          oacc[qg][ni] = __builtin_amdgcn_mfma_f32_16x16x32_bf16(pf, vf[ni], oacc[qg][ni], 0, 0, 0);
      }
    }
    __syncthreads();
  }

  // epilogue: reduce l across the 16 lanes holding each row, scale, store bf16
#pragma unroll
  for (int qg = 0; qg < 2; ++qg)
#pragma unroll
    for (int j = 0; j < 4; ++j) {
      float l = l_i[qg][j];
      l += __shfl_xor(l, 1, 64);
      l += __shfl_xor(l, 2, 64);
      l += __shfl_xor(l, 4, 64);
      l += __shfl_xor(l, 8, 64);
      const float inv = 1.0f / l;
      const int t = qt * 128 + w * 32 + qg * 16 + quad * 4 + j;
      const size_t gbase = ((size_t)((b * T_ + t) * H_ + h)) * D_;
#pragma unroll
      for (int ni = 0; ni < 4; ++ni)
        Yb[gbase + ni * 16 + r] = f2bf(oacc[qg][ni][j] * inv);
    }
}

extern "C" void kernel_launch(void* const* d_in, const int* in_sizes, int n_in,
                              void* d_out, int out_size, void* d_ws, size_t ws_size,
                              hipStream_t stream) {
  const float* x    = (const float*)d_in[0];
  const float* cosb = (const float*)d_in[1];
  const float* sinb = (const float*)d_in[2];
  const float* Wq   = (const float*)d_in[3];
  const float* Wk   = (const float*)d_in[4];
  const float* Wv   = (const float*)d_in[5];
  const float* Wo   = (const float*)d_in[6];
  float* out = (float*)d_out;

  const size_t NE = (size_t)B_ * T_ * C_;  // 8M elements
  const int CC = C_ * C_;                  // 1M elements
  // workspace (~72 MB): xb,qb,kb,vtb bf16 (64 MB) + wqkv (6 MB) + wob (2 MB)
  u16* xb   = (u16*)d_ws;
  u16* qb   = xb + NE;
  u16* kb   = qb + NE;
  u16* vtb  = kb + NE;   // V stored transposed+permuted: [(b*H+h)*D + d][T]
  u16* wqkv = vtb + NE;
  u16* wob  = wqkv + 3 * (size_t)CC;
  u16* yb   = xb;  // xb dead after QKV GEMM; reuse for attention output

  const int M = B_ * T_;  // 8192

  cvt_bf16<<<(int)(NE / 1024), 256, 0, stream>>>(x, xb, (int)NE);
  dim3 wg(CC / 1024, 4);
  cvt_weights<<<wg, 256, 0, stream>>>(Wq, Wk, Wv, Wo, wqkv, wob, CC);

  dim3 qg(24, M / 128), gb(256);
  gemm_qkv<<<qg, gb, 0, stream>>>(xb, wqkv, qb, kb, vtb, cosb, sinb, M, C_);

  dim3 fg(B_ * H_, T_ / 128);
  flash_mfma<<<fg, 256, 0, stream>>>(qb, kb, vtb, yb);

  dim3 og(C_ / 128, M / 128);
  gemm_out<<<og, gb, 0, stream>>>(yb, wob, out, M, C_, C_);
}